// Round 8
// baseline (938.554 us; speedup 1.0000x reference)
//
#include <hip/hip_runtime.h>

#define NUM_TAGS 128
#define NUM_FEATS 500000
#define BB 64
#define TT 512
#define FF 8
#define NTOK (BB * TT)                    // 32768 tokens

typedef float f2 __attribute__((ext_vector_type(2)));

// Padded alpha index: quarter g>>5 stored at stride 36 floats (144 B, 16B-aligned)
// -> the 4 per-quarter broadcast groups of a ds_read_b128 hit disjoint banks.
#define AP(j) ((((j) >> 5) * 36) + ((j) & 31))

// Raw workgroup barrier: wait LDS ops only (no vmcnt drain), so the 4-deep
// ev prefetch stays in flight across steps. sched_barrier(0) AFTER s_barrier
// keeps next-step ds_reads from hoisting above the barrier (m152-class race).
__device__ __forceinline__ void barrier_lds() {
  asm volatile("s_waitcnt lgkmcnt(0)" ::: "memory");
  __builtin_amdgcn_s_barrier();
  __builtin_amdgcn_sched_barrier(0);
}

// Quad butterfly sum via DPP (VALU pipe) — lanes 4j..4j+3 end with the 4-lane sum.
__device__ __forceinline__ float quad_sum_dpp(float r) {
  int t1 = __builtin_amdgcn_mov_dpp(__builtin_bit_cast(int, r), 0xB1, 0xF, 0xF, true);
  r += __builtin_bit_cast(float, t1);                  // quad_perm [1,0,3,2]: xor 1
  int t2 = __builtin_amdgcn_mov_dpp(__builtin_bit_cast(int, r), 0x4E, 0xF, 0xF, true);
  r += __builtin_bit_cast(float, t2);                  // quad_perm [2,3,0,1]: xor 2
  return r;
}

// G1: transpose-free gather. Block (k = bid&127, h = bid>>7) reads sw row k
// DIRECTLY, restricted to feature half h -> per-block HBM line footprint is a
// disjoint 1MB, all 256 CUs stream, row lines are L2-resident on re-hit.
// Output k-major, LOG-SPACE partial sums (fwd combines halves and exps).
// Each thread owns 2 adjacent tokens -> feats reads are full 64B lines.
template <int NH>
__global__ __launch_bounds__(512) void gather_k_kernel(
    const int* __restrict__ feats, const float* __restrict__ sw,
    float* __restrict__ emT) {
  const int k = blockIdx.x & (NUM_TAGS - 1);
  const int h = blockIdx.x >> 7;
  const unsigned lo = h * (NUM_FEATS / NH);
  const unsigned HF = NUM_FEATS / NH;
  const float* __restrict__ row = sw + (size_t)k * NUM_FEATS;
  float* __restrict__ outk = emT + (size_t)h * NUM_TAGS * NTOK + (size_t)k * NTOK;
  const int tid = threadIdx.x;
  for (int p = 0; p < NTOK / 1024; ++p) {              // 32 iterations
    const int token = p * 1024 + tid * 2;
    const int4* fp = (const int4*)(feats + (size_t)token * FF);
    const int4 a = fp[0], b2 = fp[1], c = fp[2], d = fp[3];
    float s0 = 0.f, s1 = 0.f;
    if (NH == 1) {
      s0 = ((row[a.x] + row[a.y]) + (row[a.z] + row[a.w])) +
           ((row[b2.x] + row[b2.y]) + (row[b2.z] + row[b2.w]));
      s1 = ((row[c.x] + row[c.y]) + (row[c.z] + row[c.w])) +
           ((row[d.x] + row[d.y]) + (row[d.z] + row[d.w]));
    } else {
      if ((unsigned)(a.x - lo) < HF)  s0 += row[a.x];
      if ((unsigned)(a.y - lo) < HF)  s0 += row[a.y];
      if ((unsigned)(a.z - lo) < HF)  s0 += row[a.z];
      if ((unsigned)(a.w - lo) < HF)  s0 += row[a.w];
      if ((unsigned)(b2.x - lo) < HF) s0 += row[b2.x];
      if ((unsigned)(b2.y - lo) < HF) s0 += row[b2.y];
      if ((unsigned)(b2.z - lo) < HF) s0 += row[b2.z];
      if ((unsigned)(b2.w - lo) < HF) s0 += row[b2.w];
      if ((unsigned)(c.x - lo) < HF)  s1 += row[c.x];
      if ((unsigned)(c.y - lo) < HF)  s1 += row[c.y];
      if ((unsigned)(c.z - lo) < HF)  s1 += row[c.z];
      if ((unsigned)(c.w - lo) < HF)  s1 += row[c.w];
      if ((unsigned)(d.x - lo) < HF)  s1 += row[d.x];
      if ((unsigned)(d.y - lo) < HF)  s1 += row[d.y];
      if ((unsigned)(d.z - lo) < HF)  s1 += row[d.z];
      if ((unsigned)(d.w - lo) < HF)  s1 += row[d.w];
    }
    outk[token] = s0;
    outk[token + 1] = s1;
  }
}

// expT pair (rows 32q+2I, 32q+2I+1; column j) — init for named SSA registers.
#define EINIT(I) (f2){__expf(trans[(32 * q + 2 * (I)) * NUM_TAGS + j]), \
                      __expf(trans[(32 * q + 2 * (I) + 1) * NUM_TAGS + j])}

// One forward step (R7 core, ev source changed to k-major log-space halves).
// All expT state in NAMED f2 SSA values so the "memory" clobber in barrier_lds
// cannot force scratch reloads.
#define STEP(EV, T, SRC, DST) do {                                          \
  f2 ep_ = (EV);                                                            \
  int tp_ = (T) + 4; if (tp_ > TT - 1) tp_ = TT - 1;                        \
  (EV).x = jA[tp_];                                /* prefetch 4 ahead */   \
  (EV).y = TWO ? jB[tp_] : 0.f;                                             \
  float ev_ = __expf(ep_.x + ep_.y);                                        \
  const float4* a4_ = (const float4*)((SRC) + q * 36);                      \
  float4 A0 = a4_[0], A1 = a4_[1], A2 = a4_[2], A3 = a4_[3];                \
  float4 A4 = a4_[4], A5 = a4_[5], A6 = a4_[6], A7 = a4_[7];                \
  f2 ac0 = {0.f, 0.f}, ac1 = {0.f, 0.f};                                    \
  ac0 += (f2){A0.x, A0.y} * e00;  ac1 += (f2){A0.z, A0.w} * e01;            \
  ac0 += (f2){A1.x, A1.y} * e02;  ac1 += (f2){A1.z, A1.w} * e03;            \
  ac0 += (f2){A2.x, A2.y} * e04;  ac1 += (f2){A2.z, A2.w} * e05;            \
  ac0 += (f2){A3.x, A3.y} * e06;  ac1 += (f2){A3.z, A3.w} * e07;            \
  ac0 += (f2){A4.x, A4.y} * e08;  ac1 += (f2){A4.z, A4.w} * e09;            \
  ac0 += (f2){A5.x, A5.y} * e10;  ac1 += (f2){A5.z, A5.w} * e11;            \
  ac0 += (f2){A6.x, A6.y} * e12;  ac1 += (f2){A6.z, A6.w} * e13;            \
  ac0 += (f2){A7.x, A7.y} * e14;  ac1 += (f2){A7.z, A7.w} * e15;            \
  f2 s_ = ac0 + ac1;                                                        \
  float r_ = quad_sum_dpp(s_.x + s_.y);                                     \
  if (q == 0) (DST)[AP(j)] = r_ * ev_ * 0.0078125f;  /* * 2^-7 rescale */   \
  barrier_lds();                                                            \
} while (0)

// K2: prob-space forward. 512 threads, j=tid>>2 owns output column, q=tid&3 the
// sum quarter (32 FMAs). expT slice in 16 named f2 regs. 1 barrier/step.
// Emissions arrive as log-space half-sums pA/pB, k-major [128][NTOK].
template <bool TWO>
__global__ __launch_bounds__(512, 1) void fwd_kernel(
    const float* __restrict__ pA, const float* __restrict__ pB,
    const int* __restrict__ tags, const float* __restrict__ trans,
    const float* __restrict__ startT, const float* __restrict__ endT,
    float* __restrict__ out) {
  const int b = blockIdx.x;
  const int tid = threadIdx.x;
  const int j = tid >> 2, q = tid & 3;

  __shared__ __align__(16) float alf[2][144];          // double-buffered, padded
  __shared__ float sred[16];

  f2 e00 = EINIT(0),  e01 = EINIT(1),  e02 = EINIT(2),  e03 = EINIT(3);
  f2 e04 = EINIT(4),  e05 = EINIT(5),  e06 = EINIT(6),  e07 = EINIT(7);
  f2 e08 = EINIT(8),  e09 = EINIT(9),  e10 = EINIT(10), e11 = EINIT(11);
  f2 e12 = EINIT(12), e13 = EINIT(13), e14 = EINIT(14), e15 = EINIT(15);

  const float* __restrict__ jA = pA + (size_t)j * NTOK + b * TT;  // seq in t
  const float* __restrict__ jB = pB + (size_t)j * NTOK + b * TT;

  if (q == 0) alf[0][AP(j)] = __expf(startT[j] + jA[0] + (TWO ? jB[0] : 0.f));

  f2 evA = {jA[1], TWO ? jB[1] : 0.f};
  f2 evB = {jA[2], TWO ? jB[2] : 0.f};
  f2 evC = {jA[3], TWO ? jB[3] : 0.f};
  f2 evD = {jA[4], TWO ? jB[4] : 0.f};
  __syncthreads();

  int cur = 0;
  for (int t = 1; t + 3 < TT; t += 4) {                // t = 1..505, steps t..t+3
    STEP(evA, t + 0, alf[cur], alf[cur ^ 1]); cur ^= 1;
    STEP(evB, t + 1, alf[cur], alf[cur ^ 1]); cur ^= 1;
    STEP(evC, t + 2, alf[cur], alf[cur ^ 1]); cur ^= 1;
    STEP(evD, t + 3, alf[cur], alf[cur ^ 1]); cur ^= 1;
  }
  STEP(evA, 509, alf[cur], alf[cur ^ 1]); cur ^= 1;
  STEP(evB, 510, alf[cur], alf[cur ^ 1]); cur ^= 1;
  STEP(evC, 511, alf[cur], alf[cur ^ 1]); cur ^= 1;

  // logZ: threads 0..127 (waves 0-1), reduce alpha * exp(end)
  if (tid < 128) {
    float val = alf[cur][AP(tid)] * __expf(endT[tid]);
#pragma unroll
    for (int off = 32; off > 0; off >>= 1) val += __shfl_down(val, off, 64);
    if ((tid & 63) == 0) sred[tid >> 6] = val;
  }

  // gold: thread tid handles t = tid; emission is the exact log-space sum now.
  const int* tb = tags + b * TT;
  const int t = tid;
  const int tg = tb[t];
  float g = pA[(size_t)tg * NTOK + b * TT + t];
  if (TWO) g += pB[(size_t)tg * NTOK + b * TT + t];
  if (t < TT - 1) g += trans[tg * NUM_TAGS + tb[t + 1]];
  if (t == 0) g += startT[tb[0]] + endT[tb[TT - 1]];
#pragma unroll
  for (int off = 32; off > 0; off >>= 1) g += __shfl_down(g, off, 64);
  if ((tid & 63) == 0) sred[8 + (tid >> 6)] = g;
  __syncthreads();

  if (tid == 0) {
    float logz = __logf(sred[0] + sred[1]) + 511.0f * 7.0f * 0.69314718055994531f;
    float gs = 0.f;
#pragma unroll
    for (int i = 0; i < 8; ++i) gs += sred[8 + i];
    out[b] = logz - gs;
  }
}

extern "C" void kernel_launch(void* const* d_in, const int* in_sizes, int n_in,
                              void* d_out, int out_size, void* d_ws, size_t ws_size,
                              hipStream_t stream) {
  const int* feats = (const int*)d_in[0];
  const int* tags = (const int*)d_in[1];
  const float* sw = (const float*)d_in[2];
  const float* trans = (const float*)d_in[3];
  const float* startT = (const float*)d_in[4];
  const float* endT = (const float*)d_in[5];
  float* out = (float*)d_out;

  float* part = (float*)d_ws;
  const size_t HALF_BYTES = (size_t)NUM_TAGS * NTOK * 4;   // 16 MB

  if (ws_size >= 2 * HALF_BYTES) {
    // 256 blocks = (tag k, feature half h): disjoint 1MB HBM footprints.
    gather_k_kernel<2><<<2 * NUM_TAGS, 512, 0, stream>>>(feats, sw, part);
    fwd_kernel<true><<<BB, 512, 0, stream>>>(part, part + NUM_TAGS * NTOK,
                                             tags, trans, startT, endT, out);
  } else {
    // Fallback: single-half gather (128 blocks), fwd ignores pB.
    gather_k_kernel<1><<<NUM_TAGS, 512, 0, stream>>>(feats, sw, part);
    fwd_kernel<false><<<BB, 512, 0, stream>>>(part, part,
                                              tags, trans, startT, endT, out);
  }
}

// Round 9
// 620.540 us; speedup vs baseline: 1.5125x; 1.5125x over previous
//
#include <hip/hip_runtime.h>

#define NUM_TAGS 128
#define NUM_FEATS 500000
#define BB 64
#define TT 512
#define FF 8

#define SWT_BYTES 256000000ull            // 500000*128*4
#define EM_BYTES  16777216ull             // 64*512*128*4
#define NEED_FULL (SWT_BYTES + EM_BYTES)

typedef float f2 __attribute__((ext_vector_type(2)));

// Padded alpha index: quarter g>>5 stored at stride 36 floats (144 B, 16B-aligned)
// -> the 4 per-quarter broadcast groups of a ds_read_b128 hit disjoint banks.
#define AP(j) ((((j) >> 5) * 36) + ((j) & 31))

// Raw workgroup barrier: wait LDS ops only (no vmcnt drain), so the 4-deep
// ev prefetch stays in flight across steps. sched_barrier(0) AFTER s_barrier
// keeps next-step ds_reads from hoisting above the barrier (m152-class race).
__device__ __forceinline__ void barrier_lds() {
  asm volatile("s_waitcnt lgkmcnt(0)" ::: "memory");
  __builtin_amdgcn_s_barrier();
  __builtin_amdgcn_sched_barrier(0);
}

// Quad butterfly sum via DPP (VALU pipe) — lanes 4j..4j+3 end with the 4-lane sum.
__device__ __forceinline__ float quad_sum_dpp(float r) {
  int t1 = __builtin_amdgcn_mov_dpp(__builtin_bit_cast(int, r), 0xB1, 0xF, 0xF, true);
  r += __builtin_bit_cast(float, t1);                  // quad_perm [1,0,3,2]: xor 1
  int t2 = __builtin_amdgcn_mov_dpp(__builtin_bit_cast(int, r), 0x4E, 0xF, 0xF, true);
  r += __builtin_bit_cast(float, t2);                  // quad_perm [2,3,0,1]: xor 2
  return r;
}

// T1: transpose state_weights [128][500000] -> swT [500000][128]. (round-0, proven)
__global__ __launch_bounds__(256) void transpose_kernel(
    const float* __restrict__ sw, float* __restrict__ swT) {
  __shared__ float tile[32][129];
  const int f0 = blockIdx.x * 32;
  const int t = threadIdx.x;
  const int fi = t & 31, kb = t >> 5;          // kb 0..7
#pragma unroll
  for (int it = 0; it < 16; ++it) {
    int k = kb + it * 8;
    tile[fi][k] = sw[(size_t)k * NUM_FEATS + f0 + fi];  // 128B coalesced
  }
  __syncthreads();
  const int k2 = t & 127, fo = t >> 7;         // fo 0..1
#pragma unroll
  for (int it = 0; it < 16; ++it) {
    int f2i = fo + it * 2;
    swT[(size_t)(f0 + f2i) * NUM_TAGS + k2] = tile[f2i][k2];  // 512B coalesced
  }
}

// K1a: emissions from transposed table; exp() folded. (round-0, proven)
__global__ __launch_bounds__(128) void gather_t_kernel(
    const int* __restrict__ feats, const float* __restrict__ swT,
    float* __restrict__ em_exp) {
  const int token = blockIdx.x;
  const int k = threadIdx.x;
  const int* f = feats + token * FF;
  float s = 0.f;
#pragma unroll
  for (int i = 0; i < FF; ++i) s += swT[(size_t)f[i] * NUM_TAGS + k];
  em_exp[(size_t)token * NUM_TAGS + k] = __expf(s);
}

// K1b fallback: direct strided gather. (round-0, proven)
__global__ __launch_bounds__(128) void gather_f_kernel(
    const int* __restrict__ feats, const float* __restrict__ sw,
    float* __restrict__ em_exp) {
  const int token = blockIdx.x;
  const int k = threadIdx.x;
  const int* f = feats + token * FF;
  const float* row = sw + (size_t)k * NUM_FEATS;
  float s = 0.f;
#pragma unroll
  for (int i = 0; i < FF; ++i) s += row[f[i]];
  em_exp[(size_t)token * NUM_TAGS + k] = __expf(s);
}

// expT pair (rows 32q+2I, 32q+2I+1; column j) — init for named SSA registers.
#define EINIT(I) (f2){__expf(trans[(32 * q + 2 * (I)) * NUM_TAGS + j]), \
                      __expf(trans[(32 * q + 2 * (I) + 1) * NUM_TAGS + j])}

// One DOUBLE forward step: two independent sentences (A,B) advance one step
// under a SINGLE barrier — fixed per-step costs (barrier, DS issue, waits)
// amortize 2x; interleaved A/B FMA chains double ILP. expT regs shared.
// All expT state in NAMED f2 SSA values (R6 post-mortem: arrays get alloca'd).
#define STEP2(EVA, EVB, T, SA, DA, SB, DB) do {                              \
  float eva_ = (EVA), evb_ = (EVB);                                          \
  int tp_ = (T) + 4; if (tp_ > TT - 1) tp_ = TT - 1;                         \
  (EVA) = embxA[tp_ * NUM_TAGS + j];              /* prefetch 4 ahead */     \
  (EVB) = embxB[tp_ * NUM_TAGS + j];                                         \
  const float4* pa_ = (const float4*)((SA) + q * 36);                        \
  const float4* pb_ = (const float4*)((SB) + q * 36);                        \
  float4 A0 = pa_[0], A1 = pa_[1], A2 = pa_[2], A3 = pa_[3];                 \
  float4 A4 = pa_[4], A5 = pa_[5], A6 = pa_[6], A7 = pa_[7];                 \
  float4 B0 = pb_[0], B1 = pb_[1], B2 = pb_[2], B3 = pb_[3];                 \
  float4 B4 = pb_[4], B5 = pb_[5], B6 = pb_[6], B7 = pb_[7];                 \
  f2 aa0 = {0.f, 0.f}, aa1 = {0.f, 0.f};                                     \
  f2 bb0 = {0.f, 0.f}, bb1 = {0.f, 0.f};                                     \
  aa0 += (f2){A0.x, A0.y} * e00;  aa1 += (f2){A0.z, A0.w} * e01;             \
  bb0 += (f2){B0.x, B0.y} * e00;  bb1 += (f2){B0.z, B0.w} * e01;             \
  aa0 += (f2){A1.x, A1.y} * e02;  aa1 += (f2){A1.z, A1.w} * e03;             \
  bb0 += (f2){B1.x, B1.y} * e02;  bb1 += (f2){B1.z, B1.w} * e03;             \
  aa0 += (f2){A2.x, A2.y} * e04;  aa1 += (f2){A2.z, A2.w} * e05;             \
  bb0 += (f2){B2.x, B2.y} * e04;  bb1 += (f2){B2.z, B2.w} * e05;             \
  aa0 += (f2){A3.x, A3.y} * e06;  aa1 += (f2){A3.z, A3.w} * e07;             \
  bb0 += (f2){B3.x, B3.y} * e06;  bb1 += (f2){B3.z, B3.w} * e07;             \
  aa0 += (f2){A4.x, A4.y} * e08;  aa1 += (f2){A4.z, A4.w} * e09;             \
  bb0 += (f2){B4.x, B4.y} * e08;  bb1 += (f2){B4.z, B4.w} * e09;             \
  aa0 += (f2){A5.x, A5.y} * e10;  aa1 += (f2){A5.z, A5.w} * e11;             \
  bb0 += (f2){B5.x, B5.y} * e10;  bb1 += (f2){B5.z, B5.w} * e11;             \
  aa0 += (f2){A6.x, A6.y} * e12;  aa1 += (f2){A6.z, A6.w} * e13;             \
  bb0 += (f2){B6.x, B6.y} * e12;  bb1 += (f2){B6.z, B6.w} * e13;             \
  aa0 += (f2){A7.x, A7.y} * e14;  aa1 += (f2){A7.z, A7.w} * e15;             \
  bb0 += (f2){B7.x, B7.y} * e14;  bb1 += (f2){B7.z, B7.w} * e15;             \
  f2 sa_ = aa0 + aa1, sb_ = bb0 + bb1;                                       \
  float ra_ = quad_sum_dpp(sa_.x + sa_.y);                                   \
  float rb_ = quad_sum_dpp(sb_.x + sb_.y);                                   \
  if (q == 0) {                                                              \
    (DA)[AP(j)] = ra_ * eva_ * 0.0078125f;        /* * 2^-7 rescale */       \
    (DB)[AP(j)] = rb_ * evb_ * 0.0078125f;                                   \
  }                                                                          \
  barrier_lds();                                                             \
} while (0)

// K2: prob-space forward, TWO sentences per block. 512 threads, j=tid>>2 owns
// output column, q=tid&3 the sum quarter. expT slice in 16 named f2 regs,
// shared by both sentences. 1 barrier per double-step.
__global__ __launch_bounds__(512, 1) void fwd2_kernel(
    const float* __restrict__ em_exp, const int* __restrict__ tags,
    const float* __restrict__ trans, const float* __restrict__ startT,
    const float* __restrict__ endT, float* __restrict__ out) {
  const int b0 = 2 * blockIdx.x, b1 = 2 * blockIdx.x + 1;
  const int tid = threadIdx.x;
  const int j = tid >> 2, q = tid & 3;

  __shared__ __align__(16) float alfA[2][144];         // double-buffered, padded
  __shared__ __align__(16) float alfB[2][144];
  __shared__ float sredA[16], sredB[16];

  f2 e00 = EINIT(0),  e01 = EINIT(1),  e02 = EINIT(2),  e03 = EINIT(3);
  f2 e04 = EINIT(4),  e05 = EINIT(5),  e06 = EINIT(6),  e07 = EINIT(7);
  f2 e08 = EINIT(8),  e09 = EINIT(9),  e10 = EINIT(10), e11 = EINIT(11);
  f2 e12 = EINIT(12), e13 = EINIT(13), e14 = EINIT(14), e15 = EINIT(15);

  const float* embxA = em_exp + (size_t)b0 * TT * NUM_TAGS;
  const float* embxB = em_exp + (size_t)b1 * TT * NUM_TAGS;

  if (q == 0) {
    alfA[0][AP(j)] = __expf(startT[j]) * embxA[j];
    alfB[0][AP(j)] = __expf(startT[j]) * embxB[j];
  }

  float evA0 = embxA[1 * NUM_TAGS + j], evB0 = embxA[2 * NUM_TAGS + j],
        evC0 = embxA[3 * NUM_TAGS + j], evD0 = embxA[4 * NUM_TAGS + j];
  float evA1 = embxB[1 * NUM_TAGS + j], evB1 = embxB[2 * NUM_TAGS + j],
        evC1 = embxB[3 * NUM_TAGS + j], evD1 = embxB[4 * NUM_TAGS + j];
  __syncthreads();

  int cur = 0;
  for (int t = 1; t + 3 < TT; t += 4) {                // t = 1..505, steps t..t+3
    STEP2(evA0, evA1, t + 0, alfA[cur], alfA[cur ^ 1], alfB[cur], alfB[cur ^ 1]); cur ^= 1;
    STEP2(evB0, evB1, t + 1, alfA[cur], alfA[cur ^ 1], alfB[cur], alfB[cur ^ 1]); cur ^= 1;
    STEP2(evC0, evC1, t + 2, alfA[cur], alfA[cur ^ 1], alfB[cur], alfB[cur ^ 1]); cur ^= 1;
    STEP2(evD0, evD1, t + 3, alfA[cur], alfA[cur ^ 1], alfB[cur], alfB[cur ^ 1]); cur ^= 1;
  }
  STEP2(evA0, evA1, 509, alfA[cur], alfA[cur ^ 1], alfB[cur], alfB[cur ^ 1]); cur ^= 1;
  STEP2(evB0, evB1, 510, alfA[cur], alfA[cur ^ 1], alfB[cur], alfB[cur ^ 1]); cur ^= 1;
  STEP2(evC0, evC1, 511, alfA[cur], alfA[cur ^ 1], alfB[cur], alfB[cur ^ 1]); cur ^= 1;

  // logZ: waves 0-1 reduce sentence A, waves 2-3 reduce sentence B.
  if (tid < 128) {
    float val = alfA[cur][AP(tid)] * __expf(endT[tid]);
#pragma unroll
    for (int off = 32; off > 0; off >>= 1) val += __shfl_down(val, off, 64);
    if ((tid & 63) == 0) sredA[tid >> 6] = val;
  } else if (tid < 256) {
    const int j2 = tid - 128;
    float val = alfB[cur][AP(j2)] * __expf(endT[j2]);
#pragma unroll
    for (int off = 32; off > 0; off >>= 1) val += __shfl_down(val, off, 64);
    if ((tid & 63) == 0) sredB[(tid >> 6) & 1] = val;
  }

  // gold sentence A: thread tid handles t = tid
  {
    const int* tb = tags + b0 * TT;
    const int tg = tb[tid];
    float g = __logf(embxA[tid * NUM_TAGS + tg]);
    if (tid < TT - 1) g += trans[tg * NUM_TAGS + tb[tid + 1]];
    if (tid == 0) g += startT[tb[0]] + endT[tb[TT - 1]];
#pragma unroll
    for (int off = 32; off > 0; off >>= 1) g += __shfl_down(g, off, 64);
    if ((tid & 63) == 0) sredA[8 + (tid >> 6)] = g;
  }
  // gold sentence B: thread tid handles t = tid
  {
    const int* tb = tags + b1 * TT;
    const int tg = tb[tid];
    float g = __logf(embxB[tid * NUM_TAGS + tg]);
    if (tid < TT - 1) g += trans[tg * NUM_TAGS + tb[tid + 1]];
    if (tid == 0) g += startT[tb[0]] + endT[tb[TT - 1]];
#pragma unroll
    for (int off = 32; off > 0; off >>= 1) g += __shfl_down(g, off, 64);
    if ((tid & 63) == 0) sredB[8 + (tid >> 6)] = g;
  }
  __syncthreads();

  if (tid == 0) {
    const float KLOG = 511.0f * 7.0f * 0.69314718055994531f;
    float gsA = 0.f, gsB = 0.f;
#pragma unroll
    for (int i = 0; i < 8; ++i) { gsA += sredA[8 + i]; gsB += sredB[8 + i]; }
    out[b0] = __logf(sredA[0] + sredA[1]) + KLOG - gsA;
    out[b1] = __logf(sredB[0] + sredB[1]) + KLOG - gsB;
  }
}

extern "C" void kernel_launch(void* const* d_in, const int* in_sizes, int n_in,
                              void* d_out, int out_size, void* d_ws, size_t ws_size,
                              hipStream_t stream) {
  const int* feats = (const int*)d_in[0];
  const int* tags = (const int*)d_in[1];
  const float* sw = (const float*)d_in[2];
  const float* trans = (const float*)d_in[3];
  const float* startT = (const float*)d_in[4];
  const float* endT = (const float*)d_in[5];
  float* out = (float*)d_out;

  if (ws_size >= NEED_FULL) {
    float* swT = (float*)d_ws;
    float* em_exp = (float*)((char*)d_ws + SWT_BYTES);
    transpose_kernel<<<NUM_FEATS / 32, 256, 0, stream>>>(sw, swT);
    gather_t_kernel<<<BB * TT, 128, 0, stream>>>(feats, swT, em_exp);
    fwd2_kernel<<<BB / 2, 512, 0, stream>>>(em_exp, tags, trans, startT, endT, out);
  } else {
    float* em_exp = (float*)d_ws;
    gather_f_kernel<<<BB * TT, 128, 0, stream>>>(feats, sw, em_exp);
    fwd2_kernel<<<BB / 2, 512, 0, stream>>>(em_exp, tags, trans, startT, endT, out);
  }
}

// Round 10
// 545.756 us; speedup vs baseline: 1.7197x; 1.1370x over previous
//
#include <hip/hip_runtime.h>

#define NUM_TAGS 128
#define NUM_FEATS 500000
#define BB 64
#define TT 512
#define FF 8

#define SWT_BYTES 256000000ull            // 500000*128*4
#define EM_BYTES  16777216ull             // 64*512*128*4
#define NEED_FULL (SWT_BYTES + EM_BYTES)

typedef float f2 __attribute__((ext_vector_type(2)));

// Padded alpha index: quarter g>>5 stored at stride 36 floats (144 B, 16B-aligned)
// -> the 4 per-quarter broadcast groups of a ds_read_b128 hit disjoint banks.
#define AP(j) ((((j) >> 5) * 36) + ((j) & 31))

// Raw workgroup barrier: wait LDS ops only (no vmcnt drain), so the 4-deep
// ev prefetch stays in flight across steps. sched_barrier(0) AFTER s_barrier
// keeps next-step ds_reads from hoisting above the barrier (m152-class race).
__device__ __forceinline__ void barrier_lds() {
  asm volatile("s_waitcnt lgkmcnt(0)" ::: "memory");
  __builtin_amdgcn_s_barrier();
  __builtin_amdgcn_sched_barrier(0);
}

// Quad butterfly sum via DPP (VALU pipe) — lanes 4j..4j+3 end with the 4-lane sum.
__device__ __forceinline__ float quad_sum_dpp(float r) {
  int t1 = __builtin_amdgcn_mov_dpp(__builtin_bit_cast(int, r), 0xB1, 0xF, 0xF, true);
  r += __builtin_bit_cast(float, t1);                  // quad_perm [1,0,3,2]: xor 1
  int t2 = __builtin_amdgcn_mov_dpp(__builtin_bit_cast(int, r), 0x4E, 0xF, 0xF, true);
  r += __builtin_bit_cast(float, t2);                  // quad_perm [2,3,0,1]: xor 2
  return r;
}

// T1: transpose state_weights [128][500000] -> swT [500000][128]. (round-0, proven)
__global__ __launch_bounds__(256) void transpose_kernel(
    const float* __restrict__ sw, float* __restrict__ swT) {
  __shared__ float tile[32][129];
  const int f0 = blockIdx.x * 32;
  const int t = threadIdx.x;
  const int fi = t & 31, kb = t >> 5;          // kb 0..7
#pragma unroll
  for (int it = 0; it < 16; ++it) {
    int k = kb + it * 8;
    tile[fi][k] = sw[(size_t)k * NUM_FEATS + f0 + fi];  // 128B coalesced
  }
  __syncthreads();
  const int k2 = t & 127, fo = t >> 7;         // fo 0..1
#pragma unroll
  for (int it = 0; it < 16; ++it) {
    int f2i = fo + it * 2;
    swT[(size_t)(f0 + f2i) * NUM_TAGS + k2] = tile[f2i][k2];  // 512B coalesced
  }
}

// K1a: emissions from transposed table; exp() folded. (round-0, proven)
__global__ __launch_bounds__(128) void gather_t_kernel(
    const int* __restrict__ feats, const float* __restrict__ swT,
    float* __restrict__ em_exp) {
  const int token = blockIdx.x;
  const int k = threadIdx.x;
  const int* f = feats + token * FF;
  float s = 0.f;
#pragma unroll
  for (int i = 0; i < FF; ++i) s += swT[(size_t)f[i] * NUM_TAGS + k];
  em_exp[(size_t)token * NUM_TAGS + k] = __expf(s);
}

// K1b fallback: direct strided gather. (round-0, proven)
__global__ __launch_bounds__(128) void gather_f_kernel(
    const int* __restrict__ feats, const float* __restrict__ sw,
    float* __restrict__ em_exp) {
  const int token = blockIdx.x;
  const int k = threadIdx.x;
  const int* f = feats + token * FF;
  const float* row = sw + (size_t)k * NUM_FEATS;
  float s = 0.f;
#pragma unroll
  for (int i = 0; i < FF; ++i) s += row[f[i]];
  em_exp[(size_t)token * NUM_TAGS + k] = __expf(s);
}

// expT pairs (rows 32q+2I, 32q+2I+1) for columns j (EINIT) and j+64 (FINIT).
#define EINIT(I) (f2){__expf(trans[(32 * q + 2 * (I)) * NUM_TAGS + j]), \
                      __expf(trans[(32 * q + 2 * (I) + 1) * NUM_TAGS + j])}
#define FINIT(I) (f2){__expf(trans[(32 * q + 2 * (I)) * NUM_TAGS + j + 64]), \
                      __expf(trans[(32 * q + 2 * (I) + 1) * NUM_TAGS + j + 64])}

// One forward step, 4-wave version: thread (j=tid>>2, q=tid&3) computes quarter
// q of TWO columns (j, j+64) from the SAME 8 staged float4s — DS instrs/CU/step
// halve vs R7 (the measured bottleneck: ~6.8 cy/ds_read_b128, R9 post-mortem).
// All expT state in NAMED f2 SSA values (R6: arrays get alloca'd to scratch).
#define STEP(EV, T, SRC, DST) do {                                          \
  f2 ev_ = (EV);                                                            \
  int tp_ = (T) + 4; if (tp_ > TT - 1) tp_ = TT - 1;                        \
  (EV).x = embx[tp_ * NUM_TAGS + j];              /* prefetch 4 ahead */    \
  (EV).y = embx[tp_ * NUM_TAGS + j + 64];                                   \
  const float4* a4_ = (const float4*)((SRC) + q * 36);                      \
  float4 A0 = a4_[0], A1 = a4_[1], A2 = a4_[2], A3 = a4_[3];                \
  float4 A4 = a4_[4], A5 = a4_[5], A6 = a4_[6], A7 = a4_[7];                \
  f2 ac0 = {0.f, 0.f}, ac1 = {0.f, 0.f};                                    \
  f2 bc0 = {0.f, 0.f}, bc1 = {0.f, 0.f};                                    \
  ac0 += (f2){A0.x, A0.y} * e00;  ac1 += (f2){A0.z, A0.w} * e01;            \
  bc0 += (f2){A0.x, A0.y} * f00;  bc1 += (f2){A0.z, A0.w} * f01;            \
  ac0 += (f2){A1.x, A1.y} * e02;  ac1 += (f2){A1.z, A1.w} * e03;            \
  bc0 += (f2){A1.x, A1.y} * f02;  bc1 += (f2){A1.z, A1.w} * f03;            \
  ac0 += (f2){A2.x, A2.y} * e04;  ac1 += (f2){A2.z, A2.w} * e05;            \
  bc0 += (f2){A2.x, A2.y} * f04;  bc1 += (f2){A2.z, A2.w} * f05;            \
  ac0 += (f2){A3.x, A3.y} * e06;  ac1 += (f2){A3.z, A3.w} * e07;            \
  bc0 += (f2){A3.x, A3.y} * f06;  bc1 += (f2){A3.z, A3.w} * f07;            \
  ac0 += (f2){A4.x, A4.y} * e08;  ac1 += (f2){A4.z, A4.w} * e09;            \
  bc0 += (f2){A4.x, A4.y} * f08;  bc1 += (f2){A4.z, A4.w} * f09;            \
  ac0 += (f2){A5.x, A5.y} * e10;  ac1 += (f2){A5.z, A5.w} * e11;            \
  bc0 += (f2){A5.x, A5.y} * f10;  bc1 += (f2){A5.z, A5.w} * f11;            \
  ac0 += (f2){A6.x, A6.y} * e12;  ac1 += (f2){A6.z, A6.w} * e13;            \
  bc0 += (f2){A6.x, A6.y} * f12;  bc1 += (f2){A6.z, A6.w} * f13;            \
  ac0 += (f2){A7.x, A7.y} * e14;  ac1 += (f2){A7.z, A7.w} * e15;            \
  bc0 += (f2){A7.x, A7.y} * f14;  bc1 += (f2){A7.z, A7.w} * f15;            \
  f2 sa_ = ac0 + ac1, sb_ = bc0 + bc1;                                      \
  float ra_ = quad_sum_dpp(sa_.x + sa_.y);                                  \
  float rb_ = quad_sum_dpp(sb_.x + sb_.y);                                  \
  if (q == 0) {                                                             \
    (DST)[AP(j)] = ra_ * ev_.x * 0.0078125f;      /* * 2^-7 rescale */      \
    (DST)[AP(j + 64)] = rb_ * ev_.y * 0.0078125f;                           \
  }                                                                         \
  barrier_lds();                                                            \
} while (0)

// K2: prob-space forward. 256 threads (4 waves), j=tid>>2 in [0,64), q=tid&3.
// Each thread: quarter q of columns j and j+64 (32 pk-FMA). expT in 32 named
// f2 regs. 1 lgkm-only barrier/step, 0 bank conflicts.
__global__ __launch_bounds__(256, 1) void fwd_kernel(
    const float* __restrict__ em_exp, const int* __restrict__ tags,
    const float* __restrict__ trans, const float* __restrict__ startT,
    const float* __restrict__ endT, float* __restrict__ out) {
  const int b = blockIdx.x;
  const int tid = threadIdx.x;
  const int j = tid >> 2, q = tid & 3;

  __shared__ __align__(16) float alf[2][144];          // double-buffered, padded
  __shared__ float sred[16];

  f2 e00 = EINIT(0),  e01 = EINIT(1),  e02 = EINIT(2),  e03 = EINIT(3);
  f2 e04 = EINIT(4),  e05 = EINIT(5),  e06 = EINIT(6),  e07 = EINIT(7);
  f2 e08 = EINIT(8),  e09 = EINIT(9),  e10 = EINIT(10), e11 = EINIT(11);
  f2 e12 = EINIT(12), e13 = EINIT(13), e14 = EINIT(14), e15 = EINIT(15);
  f2 f00 = FINIT(0),  f01 = FINIT(1),  f02 = FINIT(2),  f03 = FINIT(3);
  f2 f04 = FINIT(4),  f05 = FINIT(5),  f06 = FINIT(6),  f07 = FINIT(7);
  f2 f08 = FINIT(8),  f09 = FINIT(9),  f10 = FINIT(10), f11 = FINIT(11);
  f2 f12 = FINIT(12), f13 = FINIT(13), f14 = FINIT(14), f15 = FINIT(15);

  const float* embx = em_exp + (size_t)b * TT * NUM_TAGS;

  if (q == 0) {
    alf[0][AP(j)] = __expf(startT[j]) * embx[j];
    alf[0][AP(j + 64)] = __expf(startT[j + 64]) * embx[j + 64];
  }

  f2 evA = {embx[1 * NUM_TAGS + j], embx[1 * NUM_TAGS + j + 64]};
  f2 evB = {embx[2 * NUM_TAGS + j], embx[2 * NUM_TAGS + j + 64]};
  f2 evC = {embx[3 * NUM_TAGS + j], embx[3 * NUM_TAGS + j + 64]};
  f2 evD = {embx[4 * NUM_TAGS + j], embx[4 * NUM_TAGS + j + 64]};
  __syncthreads();

  int cur = 0;
  for (int t = 1; t + 3 < TT; t += 4) {                // t = 1..505, steps t..t+3
    STEP(evA, t + 0, alf[cur], alf[cur ^ 1]); cur ^= 1;
    STEP(evB, t + 1, alf[cur], alf[cur ^ 1]); cur ^= 1;
    STEP(evC, t + 2, alf[cur], alf[cur ^ 1]); cur ^= 1;
    STEP(evD, t + 3, alf[cur], alf[cur ^ 1]); cur ^= 1;
  }
  STEP(evA, 509, alf[cur], alf[cur ^ 1]); cur ^= 1;
  STEP(evB, 510, alf[cur], alf[cur ^ 1]); cur ^= 1;
  STEP(evC, 511, alf[cur], alf[cur ^ 1]); cur ^= 1;

  // logZ: threads 0..127 (waves 0-1), reduce alpha * exp(end)
  if (tid < 128) {
    float val = alf[cur][AP(tid)] * __expf(endT[tid]);
#pragma unroll
    for (int off = 32; off > 0; off >>= 1) val += __shfl_down(val, off, 64);
    if ((tid & 63) == 0) sred[tid >> 6] = val;
  }

  // gold: thread tid handles t = tid and t = tid + 256
  const int* tb = tags + b * TT;
  float g = 0.f;
#pragma unroll
  for (int p = 0; p < 2; ++p) {
    const int t = tid + 256 * p;
    const int tg = tb[t];
    g += __logf(embx[t * NUM_TAGS + tg]);
    if (t < TT - 1) g += trans[tg * NUM_TAGS + tb[t + 1]];
  }
  if (tid == 0) g += startT[tb[0]] + endT[tb[TT - 1]];
#pragma unroll
  for (int off = 32; off > 0; off >>= 1) g += __shfl_down(g, off, 64);
  if ((tid & 63) == 0) sred[8 + (tid >> 6)] = g;
  __syncthreads();

  if (tid == 0) {
    float logz = __logf(sred[0] + sred[1]) + 511.0f * 7.0f * 0.69314718055994531f;
    float gs = 0.f;
#pragma unroll
    for (int i = 0; i < 4; ++i) gs += sred[8 + i];
    out[b] = logz - gs;
  }
}

extern "C" void kernel_launch(void* const* d_in, const int* in_sizes, int n_in,
                              void* d_out, int out_size, void* d_ws, size_t ws_size,
                              hipStream_t stream) {
  const int* feats = (const int*)d_in[0];
  const int* tags = (const int*)d_in[1];
  const float* sw = (const float*)d_in[2];
  const float* trans = (const float*)d_in[3];
  const float* startT = (const float*)d_in[4];
  const float* endT = (const float*)d_in[5];
  float* out = (float*)d_out;

  if (ws_size >= NEED_FULL) {
    float* swT = (float*)d_ws;
    float* em_exp = (float*)((char*)d_ws + SWT_BYTES);
    transpose_kernel<<<NUM_FEATS / 32, 256, 0, stream>>>(sw, swT);
    gather_t_kernel<<<BB * TT, 128, 0, stream>>>(feats, swT, em_exp);
    fwd_kernel<<<BB, 256, 0, stream>>>(em_exp, tags, trans, startT, endT, out);
  } else {
    float* em_exp = (float*)d_ws;
    gather_f_kernel<<<BB * TT, 128, 0, stream>>>(feats, sw, em_exp);
    fwd_kernel<<<BB, 256, 0, stream>>>(em_exp, tags, trans, startT, endT, out);
  }
}

// Round 11
// 516.361 us; speedup vs baseline: 1.8176x; 1.0569x over previous
//
#include <hip/hip_runtime.h>
#include <hip/hip_fp16.h>

#define NUM_TAGS 128
#define NUM_FEATS 500000
#define BB 64
#define TT 512
#define FF 8

#define SWT_H_BYTES 128000000ull          // 500000*128*2 (fp16 table)
#define EM_BYTES    16777216ull           // 64*512*128*4
#define NEED_FULL   (SWT_H_BYTES + EM_BYTES)

typedef float f2 __attribute__((ext_vector_type(2)));

// Padded alpha index: quarter g>>5 stored at stride 36 floats (144 B, 16B-aligned)
// -> the 4 per-quarter broadcast groups of a ds_read_b128 hit disjoint banks.
#define AP(j) ((((j) >> 5) * 36) + ((j) & 31))

// Raw workgroup barrier: wait LDS ops only (no vmcnt drain), so the 4-deep
// ev prefetch stays in flight across steps. sched_barrier(0) AFTER s_barrier
// keeps next-step ds_reads from hoisting above the barrier (m152-class race).
__device__ __forceinline__ void barrier_lds() {
  asm volatile("s_waitcnt lgkmcnt(0)" ::: "memory");
  __builtin_amdgcn_s_barrier();
  __builtin_amdgcn_sched_barrier(0);
}

// Quad butterfly sum via DPP (VALU pipe) — lanes 4j..4j+3 end with the 4-lane sum.
__device__ __forceinline__ float quad_sum_dpp(float r) {
  int t1 = __builtin_amdgcn_mov_dpp(__builtin_bit_cast(int, r), 0xB1, 0xF, 0xF, true);
  r += __builtin_bit_cast(float, t1);                  // quad_perm [1,0,3,2]: xor 1
  int t2 = __builtin_amdgcn_mov_dpp(__builtin_bit_cast(int, r), 0x4E, 0xF, 0xF, true);
  r += __builtin_bit_cast(float, t2);                  // quad_perm [2,3,0,1]: xor 2
  return r;
}

// T1h: transpose state_weights [128][500000] -> swT fp16 [500000][128].
// Same proven tile structure as the f32 version; write stage packs __half2
// (64 half2 = 256B per feat row, coalesced). Halves transpose write traffic.
__global__ __launch_bounds__(256) void transpose_h_kernel(
    const float* __restrict__ sw, __half* __restrict__ swT) {
  __shared__ float tile[32][129];
  const int f0 = blockIdx.x * 32;
  const int t = threadIdx.x;
  const int fi = t & 31, kb = t >> 5;          // kb 0..7
#pragma unroll
  for (int it = 0; it < 16; ++it) {
    int k = kb + it * 8;
    tile[fi][k] = sw[(size_t)k * NUM_FEATS + f0 + fi];  // 128B coalesced
  }
  __syncthreads();
  const int kk = t & 63, ff = t >> 6;          // kk: half2 idx, ff 0..3
  __half2* swT2 = (__half2*)swT;
#pragma unroll
  for (int it = 0; it < 8; ++it) {
    int f2i = ff + it * 4;
    float lo = tile[f2i][2 * kk], hi = tile[f2i][2 * kk + 1];  // 2-way bank alias: free
    swT2[(size_t)(f0 + f2i) * 64 + kk] = __floats2half2_rn(lo, hi);  // 256B coalesced
  }
}

// K1a-h: emissions from the fp16 transposed table; sum in f32, exp() folded.
// Each (token, feat) row is 256B contiguous; thread k reads tag k (coalesced).
__global__ __launch_bounds__(128) void gather_th_kernel(
    const int* __restrict__ feats, const __half* __restrict__ swT,
    float* __restrict__ em_exp) {
  const int token = blockIdx.x;
  const int k = threadIdx.x;
  const int* f = feats + token * FF;
  float s = 0.f;
#pragma unroll
  for (int i = 0; i < FF; ++i)
    s += __half2float(swT[(size_t)f[i] * NUM_TAGS + k]);
  em_exp[(size_t)token * NUM_TAGS + k] = __expf(s);
}

// K1b fallback: direct strided gather from f32 sw. (round-0, proven)
__global__ __launch_bounds__(128) void gather_f_kernel(
    const int* __restrict__ feats, const float* __restrict__ sw,
    float* __restrict__ em_exp) {
  const int token = blockIdx.x;
  const int k = threadIdx.x;
  const int* f = feats + token * FF;
  const float* row = sw + (size_t)k * NUM_FEATS;
  float s = 0.f;
#pragma unroll
  for (int i = 0; i < FF; ++i) s += row[f[i]];
  em_exp[(size_t)token * NUM_TAGS + k] = __expf(s);
}

// expT pair (rows 32q+2I, 32q+2I+1; column j) — init for named SSA registers.
#define EINIT(I) (f2){__expf(trans[(32 * q + 2 * (I)) * NUM_TAGS + j]), \
                      __expf(trans[(32 * q + 2 * (I) + 1) * NUM_TAGS + j])}

// One forward step (R7 core, best measured fwd). All expT state in NAMED f2
// SSA values (e00..e15) so the "memory" clobber in barrier_lds cannot force
// scratch reloads (R6 post-mortem: array form was alloca'd).
#define STEP(EV, T, SRC, DST) do {                                          \
  float ev_ = (EV);                                                         \
  int tp_ = (T) + 4; if (tp_ > TT - 1) tp_ = TT - 1;                        \
  (EV) = embx[tp_ * NUM_TAGS + j];               /* prefetch 4 ahead */     \
  const float4* a4_ = (const float4*)((SRC) + q * 36);                      \
  float4 A0 = a4_[0], A1 = a4_[1], A2 = a4_[2], A3 = a4_[3];                \
  float4 A4 = a4_[4], A5 = a4_[5], A6 = a4_[6], A7 = a4_[7];                \
  f2 ac0 = {0.f, 0.f}, ac1 = {0.f, 0.f};                                    \
  ac0 += (f2){A0.x, A0.y} * e00;  ac1 += (f2){A0.z, A0.w} * e01;            \
  ac0 += (f2){A1.x, A1.y} * e02;  ac1 += (f2){A1.z, A1.w} * e03;            \
  ac0 += (f2){A2.x, A2.y} * e04;  ac1 += (f2){A2.z, A2.w} * e05;            \
  ac0 += (f2){A3.x, A3.y} * e06;  ac1 += (f2){A3.z, A3.w} * e07;            \
  ac0 += (f2){A4.x, A4.y} * e08;  ac1 += (f2){A4.z, A4.w} * e09;            \
  ac0 += (f2){A5.x, A5.y} * e10;  ac1 += (f2){A5.z, A5.w} * e11;            \
  ac0 += (f2){A6.x, A6.y} * e12;  ac1 += (f2){A6.z, A6.w} * e13;            \
  ac0 += (f2){A7.x, A7.y} * e14;  ac1 += (f2){A7.z, A7.w} * e15;            \
  f2 s_ = ac0 + ac1;                                                        \
  float r_ = quad_sum_dpp(s_.x + s_.y);                                     \
  if (q == 0) (DST)[AP(j)] = r_ * ev_ * 0.0078125f;  /* * 2^-7 rescale */   \
  barrier_lds();                                                            \
} while (0)

// K2: prob-space forward (R7, best measured). 512 threads, j=tid>>2 owns output
// column, q=tid&3 the sum quarter (32 FMAs). expT slice in 16 named f2 regs.
// 1 lgkm-only barrier/step, 0 bank conflicts, DPP quad reduce.
__global__ __launch_bounds__(512, 1) void fwd_kernel(
    const float* __restrict__ em_exp, const int* __restrict__ tags,
    const float* __restrict__ trans, const float* __restrict__ startT,
    const float* __restrict__ endT, float* __restrict__ out) {
  const int b = blockIdx.x;
  const int tid = threadIdx.x;
  const int j = tid >> 2, q = tid & 3;

  __shared__ __align__(16) float alf[2][144];          // double-buffered, padded
  __shared__ float sred[16];

  f2 e00 = EINIT(0),  e01 = EINIT(1),  e02 = EINIT(2),  e03 = EINIT(3);
  f2 e04 = EINIT(4),  e05 = EINIT(5),  e06 = EINIT(6),  e07 = EINIT(7);
  f2 e08 = EINIT(8),  e09 = EINIT(9),  e10 = EINIT(10), e11 = EINIT(11);
  f2 e12 = EINIT(12), e13 = EINIT(13), e14 = EINIT(14), e15 = EINIT(15);

  const float* embx = em_exp + (size_t)b * TT * NUM_TAGS;

  if (q == 0) alf[0][AP(j)] = __expf(startT[j]) * embx[j];

  float evA = embx[1 * NUM_TAGS + j], evB = embx[2 * NUM_TAGS + j],
        evC = embx[3 * NUM_TAGS + j], evD = embx[4 * NUM_TAGS + j];
  __syncthreads();

  int cur = 0;
  for (int t = 1; t + 3 < TT; t += 4) {                // t = 1..505, steps t..t+3
    STEP(evA, t + 0, alf[cur], alf[cur ^ 1]); cur ^= 1;
    STEP(evB, t + 1, alf[cur], alf[cur ^ 1]); cur ^= 1;
    STEP(evC, t + 2, alf[cur], alf[cur ^ 1]); cur ^= 1;
    STEP(evD, t + 3, alf[cur], alf[cur ^ 1]); cur ^= 1;
  }
  STEP(evA, 509, alf[cur], alf[cur ^ 1]); cur ^= 1;
  STEP(evB, 510, alf[cur], alf[cur ^ 1]); cur ^= 1;
  STEP(evC, 511, alf[cur], alf[cur ^ 1]); cur ^= 1;

  // logZ: threads 0..127 (waves 0-1), reduce alpha * exp(end)
  if (tid < 128) {
    float val = alf[cur][AP(tid)] * __expf(endT[tid]);
#pragma unroll
    for (int off = 32; off > 0; off >>= 1) val += __shfl_down(val, off, 64);
    if ((tid & 63) == 0) sred[tid >> 6] = val;
  }

  // gold: thread tid handles t = tid
  const int* tb = tags + b * TT;
  const int t = tid;
  const int tg = tb[t];
  float g = __logf(embx[t * NUM_TAGS + tg]);
  if (t < TT - 1) g += trans[tg * NUM_TAGS + tb[t + 1]];
  if (t == 0) g += startT[tb[0]] + endT[tb[TT - 1]];
#pragma unroll
  for (int off = 32; off > 0; off >>= 1) g += __shfl_down(g, off, 64);
  if ((tid & 63) == 0) sred[8 + (tid >> 6)] = g;
  __syncthreads();

  if (tid == 0) {
    float logz = __logf(sred[0] + sred[1]) + 511.0f * 7.0f * 0.69314718055994531f;
    float gs = 0.f;
#pragma unroll
    for (int i = 0; i < 8; ++i) gs += sred[8 + i];
    out[b] = logz - gs;
  }
}

extern "C" void kernel_launch(void* const* d_in, const int* in_sizes, int n_in,
                              void* d_out, int out_size, void* d_ws, size_t ws_size,
                              hipStream_t stream) {
  const int* feats = (const int*)d_in[0];
  const int* tags = (const int*)d_in[1];
  const float* sw = (const float*)d_in[2];
  const float* trans = (const float*)d_in[3];
  const float* startT = (const float*)d_in[4];
  const float* endT = (const float*)d_in[5];
  float* out = (float*)d_out;

  if (ws_size >= NEED_FULL) {
    __half* swT = (__half*)d_ws;
    float* em_exp = (float*)((char*)d_ws + SWT_H_BYTES);
    transpose_h_kernel<<<NUM_FEATS / 32, 256, 0, stream>>>(sw, swT);
    gather_th_kernel<<<BB * TT, 128, 0, stream>>>(feats, swT, em_exp);
    fwd_kernel<<<BB, 512, 0, stream>>>(em_exp, tags, trans, startT, endT, out);
  } else {
    float* em_exp = (float*)d_ws;
    gather_f_kernel<<<BB * TT, 128, 0, stream>>>(feats, sw, em_exp);
    fwd_kernel<<<BB, 512, 0, stream>>>(em_exp, tags, trans, startT, endT, out);
  }
}